// Round 10
// baseline (474.434 us; speedup 1.0000x reference)
//
#include <hip/hip_runtime.h>
#include <hip/hip_bf16.h>
#include <stdint.h>

typedef __bf16 bf16;
typedef __bf16 bf16x4 __attribute__((ext_vector_type(4)));
typedef __bf16 bf16x8 __attribute__((ext_vector_type(8)));
typedef float floatx4 __attribute__((ext_vector_type(4)));

#define MFMA16(a, b, c) __builtin_amdgcn_mfma_f32_16x16x32_bf16((a), (b), (c), 0, 0, 0)

// async global->LDS, 16B per lane; dst base wave-uniform, HW adds lane*16
static __device__ __forceinline__ void async_load16(const bf16* g, bf16* l) {
    __builtin_amdgcn_global_load_lds(
        (const __attribute__((address_space(1))) uint32_t*)(const void*)g,
        (__attribute__((address_space(3))) uint32_t*)(void*)l,
        16, 0, 0);
}

static __device__ __forceinline__ bf16x8 load8(const bf16* p) {
    return *(const bf16x8*)p;
}
static __device__ __forceinline__ bf16x8 load8(const float* p) {
    const float4 a = *(const float4*)p;
    const float4 b = *(const float4*)(p + 4);
    bf16x8 r;
    r[0] = (bf16)a.x; r[1] = (bf16)a.y; r[2] = (bf16)a.z; r[3] = (bf16)a.w;
    r[4] = (bf16)b.x; r[5] = (bf16)b.y; r[6] = (bf16)b.z; r[7] = (bf16)b.w;
    return r;
}

// ---------------------------------------------------------------------------
// f32 -> bf16 elementwise convert (n multiple of 2048)
// ---------------------------------------------------------------------------
__global__ __launch_bounds__(256) void f2b(const float* __restrict__ in,
                                           bf16* __restrict__ out) {
    const size_t i = ((size_t)blockIdx.x * 256 + threadIdx.x) * 8;
    *(bf16x8*)&out[i] = load8(in + i);
}

// ---------------------------------------------------------------------------
// Transpose f32 (R x C) -> bf16 (C x R)
// ---------------------------------------------------------------------------
__global__ __launch_bounds__(256) void transposeF2B(const float* __restrict__ in,
                                                    bf16* __restrict__ out,
                                                    int R, int C) {
    __shared__ float t[32][33];
    const int c0 = blockIdx.x * 32, r0 = blockIdx.y * 32;
    const int tx = threadIdx.x & 31, ty = threadIdx.x >> 5;
#pragma unroll
    for (int i = 0; i < 4; i++)
        t[ty + i * 8][tx] = in[(size_t)(r0 + ty + i * 8) * C + c0 + tx];
    __syncthreads();
#pragma unroll
    for (int i = 0; i < 4; i++)
        out[(size_t)(c0 + ty + i * 8) * R + r0 + tx] = (bf16)t[tx][ty + i * 8];
}

// ---------------------------------------------------------------------------
// Fused QKV GEMM: C(M x 5120) = Ab(M x 2048, bf16) * WqkvT^T.
// R13: BK=64 swizzled tiles (R12, conflict-free verified) + DOUBLE-BUFFER
// with counted vmcnt (the R11-attn-proven pattern): STAGE(t+1) issued
// before compute(t); s_waitcnt vmcnt(8) waits only tile t's 8 per-wave
// DMAs (loop body has no other VMEM -> count exact); raw s_barrier (NOT
// __syncthreads, which drains vmcnt(0)) + sched_barrier(0) fence; trailing
// s_barrier before the consumed buffer is re-staged.
// Epilogue routes: n<4096 -> Q ; 4096..4608 -> K ; >=4608 -> Vt (transposed).
// ---------------------------------------------------------------------------
__global__ __launch_bounds__(256) void gemm_qkv(const bf16* __restrict__ A,
                                                const bf16* __restrict__ BT,
                                                bf16* __restrict__ Q,
                                                bf16* __restrict__ K2,
                                                bf16* __restrict__ Vt) {
    constexpr int K = 2048;
    __shared__ __attribute__((aligned(16))) bf16 As[2][128 * 64];
    __shared__ __attribute__((aligned(16))) bf16 Bs[2][128 * 64];
    const int tid = threadIdx.x;
    const int wave = tid >> 6, lane = tid & 63;
    const int quad = lane >> 4, l16 = lane & 15;
    const int m0 = blockIdx.y * 128, n0 = blockIdx.x * 128;
    const int wr = (wave >> 1) * 64, wc = (wave & 1) * 64;

    floatx4 acc[4][4] = {};

    // DMA: per wave 4 A-chunks + 4 B-chunks (8 rows x 64 k each).
    // chunk j: rows wave*32+8j..+7; lane n -> row +(n>>3), pslot n&7,
    // source carries logical slot (n&7)^(row&7).
    const int wbase = wave * 32;
    const bf16* aSrc[4]; const bf16* bSrc[4];
#pragma unroll
    for (int j = 0; j < 4; j++) {
        const int r = wbase + 8 * j + (lane >> 3);
        aSrc[j] = A + (size_t)(m0 + r) * K + (((lane & 7) ^ (r & 7)) << 3);
        bSrc[j] = BT + (size_t)(n0 + r) * K + (((lane & 7) ^ (r & 7)) << 3);
    }

#define GSTAGE(buf, kk)                                                 \
    do {                                                                \
        bf16* aD_ = &As[buf][wbase * 64];                               \
        bf16* bD_ = &Bs[buf][wbase * 64];                               \
        _Pragma("unroll")                                               \
        for (int j_ = 0; j_ < 4; j_++) {                                \
            async_load16(aSrc[j_] + (kk), aD_ + j_ * 8 * 64);           \
            async_load16(bSrc[j_] + (kk), bD_ + j_ * 8 * 64);           \
        }                                                               \
    } while (0)

    constexpr int NKT = K / 64;
    GSTAGE(0, 0);
    int cur = 0;
    for (int kt = 0; kt < NKT; ++kt) {
        if (kt + 1 < NKT) {
            GSTAGE(cur ^ 1, (kt + 1) * 64);
            asm volatile("s_waitcnt vmcnt(8)" ::: "memory");  // tile t's DMAs done
        } else {
            asm volatile("s_waitcnt vmcnt(0)" ::: "memory");
        }
        __builtin_amdgcn_s_barrier();
        __builtin_amdgcn_sched_barrier(0);

#pragma unroll
        for (int ks = 0; ks < 2; ks++) {
            const int slot = ((ks * 4 + quad) ^ (l16 & 7)) << 3;
            bf16x8 af[4], bfr[4];
#pragma unroll
            for (int i = 0; i < 4; i++)
                af[i] = *(const bf16x8*)&As[cur][(wr + i * 16 + l16) * 64 + slot];
#pragma unroll
            for (int j = 0; j < 4; j++)
                bfr[j] = *(const bf16x8*)&Bs[cur][(wc + j * 16 + l16) * 64 + slot];
#pragma unroll
            for (int i = 0; i < 4; i++)
#pragma unroll
                for (int j = 0; j < 4; j++)
                    acc[i][j] = MFMA16(af[i], bfr[j], acc[i][j]);
        }
        __builtin_amdgcn_s_barrier();   // buf cur consumed by all waves
        cur ^= 1;
    }
#undef GSTAGE

    const int region = (n0 >= 4608) ? 2 : (n0 >= 4096 ? 1 : 0);
#pragma unroll
    for (int i = 0; i < 4; i++) {
#pragma unroll
        for (int j = 0; j < 4; j++) {
            const int row = m0 + wr + i * 16 + quad * 4;
            const int col = n0 + wc + j * 16 + l16;
            if (region == 0) {
#pragma unroll
                for (int r = 0; r < 4; r++)
                    Q[(size_t)(row + r) * 4096 + col] = (bf16)acc[i][j][r];
            } else if (region == 1) {
#pragma unroll
                for (int r = 0; r < 4; r++)
                    K2[(size_t)(row + r) * 512 + (col - 4096)] = (bf16)acc[i][j][r];
            } else {
                bf16x4 t;
#pragma unroll
                for (int r = 0; r < 4; r++) t[r] = (bf16)acc[i][j][r];
                *(bf16x4*)&Vt[(size_t)(col - 4608) * 4096 + row] = t;
            }
        }
    }
}

// ---------------------------------------------------------------------------
// O-projection GEMM: out(M x 2048, f32) = AO(M x 4096, bf16) * woT^T.
// R13: same dbuf + counted-vmcnt structure as gemm_qkv.
// ---------------------------------------------------------------------------
__global__ __launch_bounds__(256) void gemm_o(const bf16* __restrict__ A,
                                              const bf16* __restrict__ BT,
                                              float* __restrict__ C) {
    constexpr int K = 4096, N = 2048;
    __shared__ __attribute__((aligned(16))) bf16 As[2][128 * 64];
    __shared__ __attribute__((aligned(16))) bf16 Bs[2][128 * 64];
    const int tid = threadIdx.x;
    const int wave = tid >> 6, lane = tid & 63;
    const int quad = lane >> 4, l16 = lane & 15;
    const int m0 = blockIdx.y * 128, n0 = blockIdx.x * 128;
    const int wr = (wave >> 1) * 64, wc = (wave & 1) * 64;

    floatx4 acc[4][4] = {};

    const int wbase = wave * 32;
    const bf16* aSrc[4]; const bf16* bSrc[4];
#pragma unroll
    for (int j = 0; j < 4; j++) {
        const int r = wbase + 8 * j + (lane >> 3);
        aSrc[j] = A + (size_t)(m0 + r) * K + (((lane & 7) ^ (r & 7)) << 3);
        bSrc[j] = BT + (size_t)(n0 + r) * K + (((lane & 7) ^ (r & 7)) << 3);
    }

#define GSTAGE(buf, kk)                                                 \
    do {                                                                \
        bf16* aD_ = &As[buf][wbase * 64];                               \
        bf16* bD_ = &Bs[buf][wbase * 64];                               \
        _Pragma("unroll")                                               \
        for (int j_ = 0; j_ < 4; j_++) {                                \
            async_load16(aSrc[j_] + (kk), aD_ + j_ * 8 * 64);           \
            async_load16(bSrc[j_] + (kk), bD_ + j_ * 8 * 64);           \
        }                                                               \
    } while (0)

    constexpr int NKT = K / 64;
    GSTAGE(0, 0);
    int cur = 0;
    for (int kt = 0; kt < NKT; ++kt) {
        if (kt + 1 < NKT) {
            GSTAGE(cur ^ 1, (kt + 1) * 64);
            asm volatile("s_waitcnt vmcnt(8)" ::: "memory");
        } else {
            asm volatile("s_waitcnt vmcnt(0)" ::: "memory");
        }
        __builtin_amdgcn_s_barrier();
        __builtin_amdgcn_sched_barrier(0);

#pragma unroll
        for (int ks = 0; ks < 2; ks++) {
            const int slot = ((ks * 4 + quad) ^ (l16 & 7)) << 3;
            bf16x8 af[4], bfr[4];
#pragma unroll
            for (int i = 0; i < 4; i++)
                af[i] = *(const bf16x8*)&As[cur][(wr + i * 16 + l16) * 64 + slot];
#pragma unroll
            for (int j = 0; j < 4; j++)
                bfr[j] = *(const bf16x8*)&Bs[cur][(wc + j * 16 + l16) * 64 + slot];
#pragma unroll
            for (int i = 0; i < 4; i++)
#pragma unroll
                for (int j = 0; j < 4; j++)
                    acc[i][j] = MFMA16(af[i], bfr[j], acc[i][j]);
        }
        __builtin_amdgcn_s_barrier();
        cur ^= 1;
    }
#undef GSTAGE

#pragma unroll
    for (int i = 0; i < 4; i++) {
#pragma unroll
        for (int j = 0; j < 4; j++) {
            const int row = m0 + wr + i * 16 + quad * 4;
            const int col = n0 + wc + j * 16 + l16;
#pragma unroll
            for (int r = 0; r < 4; r++)
                C[(size_t)(row + r) * N + col] = acc[i][j][r];
        }
    }
}

// ---------------------------------------------------------------------------
// Fused RMSNorm (D=128) + RoPE, in place on bf16 x.
// ---------------------------------------------------------------------------
__global__ __launch_bounds__(256) void rmsrope(bf16* __restrict__ x,
                                               const float* __restrict__ w,
                                               const float* __restrict__ cosb,
                                               const float* __restrict__ sinb,
                                               int nh, int S) {
    const int lane = threadIdx.x & 63;
    const int row = blockIdx.x * 4 + (threadIdx.x >> 6);
    const int s = (row / nh) % S;
    bf16* p = x + (size_t)row * 128;
    float x1 = (float)p[lane];
    float x2 = (float)p[lane + 64];
    float ssq = x1 * x1 + x2 * x2;
#pragma unroll
    for (int m = 1; m < 64; m <<= 1) ssq += __shfl_xor(ssq, m);
    const float r = rsqrtf(ssq * (1.0f / 128.0f) + 1e-6f);
    const float y1 = w[lane] * x1 * r;
    const float y2 = w[lane + 64] * x2 * r;
    const float c1 = cosb[s * 128 + lane];
    const float s1 = sinb[s * 128 + lane];
    const float c2 = cosb[s * 128 + lane + 64];
    const float s2 = sinb[s * 128 + lane + 64];
    p[lane] = (bf16)(y1 * c1 - y2 * s1);
    p[lane + 64] = (bf16)(y2 * c2 + y1 * s2);
}

// ---------------------------------------------------------------------------
// Causal GQA flash attention. R11 structure (verified, <118us):
//  512 threads / 8 waves, Q-tile 128; causal pairing {x, 15-x}; DMA
//  double-buffer with counted vmcnt(4); raw s_barrier + sched_barrier.
// QO: (B*S x 4096); K: (B*S x 512); Vt: (512 x B*S) d-major.
// grid (S/256, HQ, B), 512 threads.
// ---------------------------------------------------------------------------
__global__ __launch_bounds__(512, 4) void attn(bf16* QO,
                                               const bf16* __restrict__ Km,
                                               const bf16* __restrict__ Vt,
                                               int S) {
    // K tile [64][128]: 16B slot s of row r at physical s ^ (r&7)
    // V tile [128][64]: 16B slot s (ki/8) of d-row r at physical s ^ (r&7)
    __shared__ __attribute__((aligned(16))) bf16 Kl[2][64 * 128];
    __shared__ __attribute__((aligned(16))) bf16 Vl[2][128 * 64];
    __shared__ __attribute__((aligned(16))) bf16 Pl[8][16 * 40]; // per-wave P

    const int tid = threadIdx.x, wave = tid >> 6, lane = tid & 63;
    const int quad = lane >> 4, l16 = lane & 15;
    const int h = blockIdx.y, b = blockIdx.z;
    const int kvh = h >> 3;
    const float scale = 0.08838834764831845f;

    const bf16* Kg = Km + (size_t)b * S * 512 + kvh * 128;
    const bf16* Vg = Vt + (size_t)kvh * 128 * 4096 + (size_t)b * S;

    const int krow0 = wave * 8 + (lane >> 4);
    const int krow1 = wave * 8 + 4 + (lane >> 4);
    const bf16* kSrc0 = Kg + (size_t)krow0 * 512 + (((lane & 15) ^ (krow0 & 7)) << 3);
    const bf16* kSrc1 = Kg + (size_t)krow1 * 512 + (((lane & 15) ^ (krow1 & 7)) << 3);
    const int vrow0 = wave * 16 + (lane >> 3);
    const int vrow1 = wave * 16 + 8 + (lane >> 3);
    const bf16* vSrc0 = Vg + (size_t)vrow0 * 4096 + (((lane & 7) ^ (vrow0 & 7)) << 3);
    const bf16* vSrc1 = Vg + (size_t)vrow1 * 4096 + (((lane & 7) ^ (vrow1 & 7)) << 3);

#define STAGE(buf, kk)                                                  \
    do {                                                                \
        bf16* kb_ = &Kl[buf][(wave * 8) * 128];                         \
        bf16* vb_ = &Vl[buf][(wave * 16) * 64];                         \
        async_load16(kSrc0 + (size_t)(kk) * 512, kb_);                  \
        async_load16(kSrc1 + (size_t)(kk) * 512, kb_ + 4 * 128);        \
        async_load16(vSrc0 + (kk), vb_);                                \
        async_load16(vSrc1 + (kk), vb_ + 8 * 64);                       \
    } while (0)

    bf16* pw = &Pl[wave][0];

#pragma unroll
    for (int half = 0; half < 2; half++) {
        const int qt = half ? (15 - blockIdx.x) : blockIdx.x;
        const int qb = qt * 128 + wave * 16;

        bf16x8 qf[4];
        {
            const bf16* qrow = QO + (size_t)(b * S + qb + l16) * 4096 + h * 128 + quad * 8;
#pragma unroll
            for (int c = 0; c < 4; c++) qf[c] = *(const bf16x8*)(qrow + c * 32);
        }

        floatx4 o_acc[8] = {};
        float l_i[4] = {0.f, 0.f, 0.f, 0.f};

        const int nt = 2 * (qt + 1);   // k-tiles of 64, block-uniform
        STAGE(0, 0);                   // prologue

        for (int kt = 0; kt < nt; ++kt) {
            const int k0 = kt * 64;
            const int cur = kt & 1;
            if (kt + 1 < nt) {
                STAGE(cur ^ 1, (kt + 1) * 64);
                asm volatile("s_waitcnt vmcnt(4)" ::: "memory");  // tile t's 4 DMAs done
            } else {
                asm volatile("s_waitcnt vmcnt(0)" ::: "memory");
            }
            __builtin_amdgcn_s_barrier();
            __builtin_amdgcn_sched_barrier(0);

            if (k0 <= qb + 15) {   // wave-uniform: skip fully-masked tiles
                const bf16* kl = &Kl[cur][0];
                const bf16* vl = &Vl[cur][0];

                floatx4 sc[4] = {};
#pragma unroll
                for (int c = 0; c < 4; c++) {
                    const int slot = ((c * 4 + quad) ^ (l16 & 7)) << 3;
#pragma unroll
                    for (int m = 0; m < 4; m++) {
                        const bf16x8 kf = *(const bf16x8*)&kl[(l16 + 16 * m) * 128 + slot];
                        sc[m] = MFMA16(qf[c], kf, sc[m]);
                    }
                }

#pragma unroll
                for (int ks = 0; ks < 2; ks++) {
                    const int kb = k0 + ks * 32;
                    if (kb > qb + 15) continue;          // fully masked half
                    const floatx4 s0 = sc[2 * ks], s1 = sc[2 * ks + 1];
                    if (kb + 31 > qb) {
#pragma unroll
                        for (int r = 0; r < 4; r++) {
                            const int qi = qb + quad * 4 + r;
                            const float p0 = (kb + l16 > qi) ? 0.f : __expf(s0[r] * scale);
                            const float p1 = (kb + 16 + l16 > qi) ? 0.f : __expf(s1[r] * scale);
                            l_i[r] += p0 + p1;
                            pw[(quad * 4 + r) * 40 + l16] = (bf16)p0;
                            pw[(quad * 4 + r) * 40 + l16 + 16] = (bf16)p1;
                        }
                    } else {
#pragma unroll
                        for (int r = 0; r < 4; r++) {
                            const float p0 = __expf(s0[r] * scale);
                            const float p1 = __expf(s1[r] * scale);
                            l_i[r] += p0 + p1;
                            pw[(quad * 4 + r) * 40 + l16] = (bf16)p0;
                            pw[(quad * 4 + r) * 40 + l16 + 16] = (bf16)p1;
                        }
                    }
                    const bf16x8 pa = *(const bf16x8*)&pw[l16 * 40 + quad * 8];
#pragma unroll
                    for (int c = 0; c < 8; c++) {
                        const int vps = ((ks * 4 + quad) ^ (l16 & 7)) << 3;
                        const bf16x8 vf = *(const bf16x8*)&vl[(c * 16 + l16) * 64 + vps];
                        o_acc[c] = MFMA16(pa, vf, o_acc[c]);
                    }
                }
            }
            __builtin_amdgcn_s_barrier();   // buf cur consumed by all waves
        }

#pragma unroll
        for (int r = 0; r < 4; r++) {
            float l = l_i[r];
            l += __shfl_xor(l, 1);
            l += __shfl_xor(l, 2);
            l += __shfl_xor(l, 4);
            l += __shfl_xor(l, 8);
            const float inv = (l > 0.f) ? 1.0f / l : 0.f;
            const size_t orow = (size_t)(b * S + qb + quad * 4 + r) * 4096 + h * 128;
#pragma unroll
            for (int c = 0; c < 8; c++)
                QO[orow + c * 16 + l16] = (bf16)(o_acc[c][r] * inv);
        }
    }
#undef STAGE
}

// ===========================================================================
// Fallback path (Round-4, proven; used only if ws_size < fast-path need)
// ===========================================================================
template <typename TA, typename TB, typename TC>
__global__ __launch_bounds__(256) void gemm_bn(const TA* __restrict__ A,
                                               const TB* __restrict__ B,
                                               TC* __restrict__ C,
                                               int M, int N, int K) {
    __shared__ __attribute__((aligned(16))) bf16 As[128 * 32];
    __shared__ __attribute__((aligned(16))) bf16 Bs[128 * 32];
    const int tid = threadIdx.x;
    const int wave = tid >> 6, lane = tid & 63;
    const int quad = lane >> 4, l16 = lane & 15;
    const int m0 = blockIdx.y * 128, n0 = blockIdx.x * 128;
    const int wr = (wave >> 1) * 64, wc = (wave & 1) * 64;
    floatx4 acc[4][4] = {};
    const int r0 = tid >> 2;
    const int kc = (tid & 3) * 8;
    const TA* gA0 = A + (size_t)(m0 + r0) * K + kc;
    const TA* gA1 = A + (size_t)(m0 + 64 + r0) * K + kc;
    const int kr = tid & 31;
    const int nc8 = (tid >> 5) * 8;
    const TB* gB = B + (size_t)kr * N + n0 + nc8;
    for (int k0 = 0; k0 < K; k0 += 32) {
        const bf16x8 a0 = load8(gA0 + k0);
        const bf16x8 a1 = load8(gA1 + k0);
        const TB* gBk = gB + (size_t)k0 * N;
        const bf16x8 b0 = load8(gBk);
        const bf16x8 b1 = load8(gBk + 64);
        __syncthreads();
        *(bf16x8*)&As[r0 * 32 + kc] = a0;
        *(bf16x8*)&As[(64 + r0) * 32 + kc] = a1;
#pragma unroll
        for (int j = 0; j < 8; j++) {
            Bs[(nc8 + j) * 32 + kr] = b0[j];
            Bs[(nc8 + 64 + j) * 32 + kr] = b1[j];
        }
        __syncthreads();
        bf16x8 af[4], bfr[4];
#pragma unroll
        for (int i = 0; i < 4; i++)
            af[i] = *(const bf16x8*)&As[(wr + i * 16 + l16) * 32 + quad * 8];
#pragma unroll
        for (int j = 0; j < 4; j++)
            bfr[j] = *(const bf16x8*)&Bs[(wc + j * 16 + l16) * 32 + quad * 8];
#pragma unroll
        for (int i = 0; i < 4; i++)
#pragma unroll
            for (int j = 0; j < 4; j++)
                acc[i][j] = MFMA16(af[i], bfr[j], acc[i][j]);
    }
#pragma unroll
    for (int i = 0; i < 4; i++) {
#pragma unroll
        for (int j = 0; j < 4; j++) {
            const int row = m0 + wr + i * 16 + quad * 4;
            const int col = n0 + wc + j * 16 + l16;
#pragma unroll
            for (int r = 0; r < 4; r++)
                C[(size_t)(row + r) * N + col] = (TC)acc[i][j][r];
        }
    }
}

__global__ __launch_bounds__(256) void attn_fb(bf16* QO,
                                               const bf16* __restrict__ Km,
                                               const bf16* __restrict__ Vm,
                                               int S) {
    __shared__ __attribute__((aligned(16))) bf16 Kl[32 * 136];
    __shared__ __attribute__((aligned(16))) bf16 Vl[128 * 40];
    __shared__ __attribute__((aligned(16))) bf16 Pl[4][16 * 40];
    const int tid = threadIdx.x, wave = tid >> 6, lane = tid & 63;
    const int quad = lane >> 4, l16 = lane & 15;
    const int q0 = blockIdx.x * 64;
    const int h = blockIdx.y, b = blockIdx.z;
    const int kvh = h >> 3;
    const int q_base = q0 + wave * 16;
    const float scale = 0.08838834764831845f;
    bf16x8 qf[4];
    {
        const bf16* qrow = QO + (size_t)(b * S + q_base + l16) * 4096 + h * 128 + quad * 8;
#pragma unroll
        for (int c = 0; c < 4; c++) qf[c] = *(const bf16x8*)(qrow + c * 32);
    }
    floatx4 o_acc[8] = {};
    float l_i[4] = {0.f, 0.f, 0.f, 0.f};
    const int kend = q0 + 64;
    for (int k0 = 0; k0 < kend; k0 += 32) {
#pragma unroll
        for (int it = 0; it < 2; ++it) {
            const int cc = tid + it * 256;
            const int row = cc >> 4;
            const int off = (cc & 15) * 8;
            const size_t gidx = (size_t)(b * S + k0 + row) * 512 + kvh * 128 + off;
            const bf16x8 kv = *(const bf16x8*)&Km[gidx];
            const bf16x8 vv = *(const bf16x8*)&Vm[gidx];
            *(bf16x8*)&Kl[row * 136 + off] = kv;
#pragma unroll
            for (int j = 0; j < 8; j++) Vl[(off + j) * 40 + row] = vv[j];
        }
        __syncthreads();
        if (k0 <= q_base + 15) {
            floatx4 sc0 = {}, sc1 = {};
#pragma unroll
            for (int c = 0; c < 4; c++) {
                bf16x8 b0 = *(const bf16x8*)&Kl[l16 * 136 + c * 32 + quad * 8];
                bf16x8 b1 = *(const bf16x8*)&Kl[(l16 + 16) * 136 + c * 32 + quad * 8];
                sc0 = MFMA16(qf[c], b0, sc0);
                sc1 = MFMA16(qf[c], b1, sc1);
            }
            const bool edge = (k0 + 31 > q_base);
            bf16* pw = &Pl[wave][0];
#pragma unroll
            for (int r = 0; r < 4; r++) {
                const int qi = q_base + quad * 4 + r;
                const bool mk0 = edge && (k0 + l16 > qi);
                const bool mk1 = edge && (k0 + 16 + l16 > qi);
                const float p0 = mk0 ? 0.f : __expf(sc0[r] * scale);
                const float p1 = mk1 ? 0.f : __expf(sc1[r] * scale);
                l_i[r] += p0 + p1;
                pw[(quad * 4 + r) * 40 + l16] = (bf16)p0;
                pw[(quad * 4 + r) * 40 + l16 + 16] = (bf16)p1;
            }
            const bf16x8 pa = *(const bf16x8*)&pw[l16 * 40 + quad * 8];
#pragma unroll
            for (int c = 0; c < 8; c++) {
                const bf16x8 vf = *(const bf16x8*)&Vl[(c * 16 + l16) * 40 + quad * 8];
                o_acc[c] = MFMA16(pa, vf, o_acc[c]);
            }
        }
        __syncthreads();
    }
#pragma unroll
    for (int r = 0; r < 4; r++) {
        float l = l_i[r];
        l += __shfl_xor(l, 1);
        l += __shfl_xor(l, 2);
        l += __shfl_xor(l, 4);
        l += __shfl_xor(l, 8);
        const float inv = (l > 0.f) ? 1.0f / l : 0.f;
        const size_t orow = (size_t)(b * S + q_base + quad * 4 + r) * 4096 + h * 128;
#pragma unroll
        for (int c = 0; c < 8; c++)
            QO[orow + c * 16 + l16] = (bf16)(o_acc[c][r] * inv);
    }
}

// ---------------------------------------------------------------------------
extern "C" void kernel_launch(void* const* d_in, const int* in_sizes, int n_in,
                              void* d_out, int out_size, void* d_ws, size_t ws_size,
                              hipStream_t stream) {
    const float* hidden = (const float*)d_in[0];
    const float* cosb = (const float*)d_in[1];
    const float* sinb = (const float*)d_in[2];
    const float* wq = (const float*)d_in[3];
    const float* wk = (const float*)d_in[4];
    const float* wv = (const float*)d_in[5];
    const float* wo = (const float*)d_in[6];
    const float* qnw = (const float*)d_in[7];
    const float* knw = (const float*)d_in[8];
    float* out = (float*)d_out;

    constexpr int B = 2, S = 2048, HID = 2048, HQ = 32, HKV = 4, D = 128;
    constexpr int M = B * S;       // 4096
    constexpr int NQ = HQ * D;     // 4096
    constexpr int NKV = HKV * D;   // 512
    constexpr int NQKV = NQ + 2 * NKV;  // 5120

    // fast-path ws need (same as R5-proven 79.7MB): X slot is shared by
    // hiddenB (M*HID) and woT (HID*NQ) -- identical element counts.
    const size_t need = ((size_t)NQKV * HID + (size_t)HID * NQ +
                         (size_t)M * NQ + 2 * (size_t)M * NKV) * sizeof(bf16);

    if (ws_size >= need) {
        bf16* p = (bf16*)d_ws;
        bf16* wqkvT = p; p += (size_t)NQKV * HID;   // (5120 x 2048)
        bf16* X = p;     p += (size_t)HID * NQ;     // hiddenB then woT (8.39e6 el)
        bf16* Qb = p;    p += (size_t)M * NQ;
        bf16* Kb = p;    p += (size_t)M * NKV;
        bf16* Vt = p;    p += (size_t)NKV * M;      // (512 x 4096) d-major

        transposeF2B<<<dim3(NQ / 32, HID / 32), 256, 0, stream>>>(wq, wqkvT, HID, NQ);
        transposeF2B<<<dim3(NKV / 32, HID / 32), 256, 0, stream>>>(wk, wqkvT + (size_t)NQ * HID, HID, NKV);
        transposeF2B<<<dim3(NKV / 32, HID / 32), 256, 0, stream>>>(wv, wqkvT + (size_t)(NQ + NKV) * HID, HID, NKV);

        // hidden f32 -> bf16 into X
        f2b<<<dim3((M * HID) / (256 * 8)), 256, 0, stream>>>(hidden, X);

        gemm_qkv<<<dim3(NQKV / 128, M / 128), 256, 0, stream>>>(X, wqkvT, Qb, Kb, Vt);

        rmsrope<<<dim3(M * HQ / 4), 256, 0, stream>>>(Qb, qnw, cosb, sinb, HQ, S);
        rmsrope<<<dim3(M * HKV / 4), 256, 0, stream>>>(Kb, knw, cosb, sinb, HKV, S);

        attn<<<dim3(S / 256, HQ, B), 512, 0, stream>>>(Qb, Kb, Vt, S);

        // X reused: wo^T lands where hiddenB was (stream-ordered, safe)
        transposeF2B<<<dim3(HID / 32, NQ / 32), 256, 0, stream>>>(wo, X, NQ, HID);
        gemm_o<<<dim3(HID / 128, M / 128), 256, 0, stream>>>(Qb, X, out);
    } else {
        bf16* p = (bf16*)d_ws;
        bf16* Qb = p;  p += (size_t)M * NQ;
        bf16* Kb = p;  p += (size_t)M * NKV;
        bf16* Vb = p;  p += (size_t)M * NKV;

        gemm_bn<float, float, bf16><<<dim3(NQ / 128, M / 128), 256, 0, stream>>>(hidden, wq, Qb, M, NQ, HID);
        gemm_bn<float, float, bf16><<<dim3(NKV / 128, M / 128), 256, 0, stream>>>(hidden, wk, Kb, M, NKV, HID);
        gemm_bn<float, float, bf16><<<dim3(NKV / 128, M / 128), 256, 0, stream>>>(hidden, wv, Vb, M, NKV, HID);
        rmsrope<<<dim3(M * HQ / 4), 256, 0, stream>>>(Qb, qnw, cosb, sinb, HQ, S);
        rmsrope<<<dim3(M * HKV / 4), 256, 0, stream>>>(Kb, knw, cosb, sinb, HKV, S);
        attn_fb<<<dim3(S / 64, HQ, B), 256, 0, stream>>>(Qb, Kb, Vb, S);
        gemm_bn<bf16, float, float><<<dim3(HID / 128, M / 128), 256, 0, stream>>>(Qb, wo, out, M, HID, NQ);
    }
}

// Round 11
// 459.276 us; speedup vs baseline: 1.0330x; 1.0330x over previous
//
#include <hip/hip_runtime.h>
#include <hip/hip_bf16.h>
#include <stdint.h>

typedef __bf16 bf16;
typedef __bf16 bf16x4 __attribute__((ext_vector_type(4)));
typedef __bf16 bf16x8 __attribute__((ext_vector_type(8)));
typedef float floatx4 __attribute__((ext_vector_type(4)));

#define MFMA16(a, b, c) __builtin_amdgcn_mfma_f32_16x16x32_bf16((a), (b), (c), 0, 0, 0)

// async global->LDS, 16B per lane; dst base wave-uniform, HW adds lane*16
static __device__ __forceinline__ void async_load16(const bf16* g, bf16* l) {
    __builtin_amdgcn_global_load_lds(
        (const __attribute__((address_space(1))) uint32_t*)(const void*)g,
        (__attribute__((address_space(3))) uint32_t*)(void*)l,
        16, 0, 0);
}

static __device__ __forceinline__ bf16x8 load8(const bf16* p) {
    return *(const bf16x8*)p;
}
static __device__ __forceinline__ bf16x8 load8(const float* p) {
    const float4 a = *(const float4*)p;
    const float4 b = *(const float4*)(p + 4);
    bf16x8 r;
    r[0] = (bf16)a.x; r[1] = (bf16)a.y; r[2] = (bf16)a.z; r[3] = (bf16)a.w;
    r[4] = (bf16)b.x; r[5] = (bf16)b.y; r[6] = (bf16)b.z; r[7] = (bf16)b.w;
    return r;
}

// ---------------------------------------------------------------------------
// f32 -> bf16 elementwise convert (n multiple of 2048)
// ---------------------------------------------------------------------------
__global__ __launch_bounds__(256) void f2b(const float* __restrict__ in,
                                           bf16* __restrict__ out) {
    const size_t i = ((size_t)blockIdx.x * 256 + threadIdx.x) * 8;
    *(bf16x8*)&out[i] = load8(in + i);
}

// ---------------------------------------------------------------------------
// Transpose f32 (R x C) -> bf16 (C x R).
// R14: vectorized bf16x4 output writes (was scalar bf16 stores).
// ---------------------------------------------------------------------------
__global__ __launch_bounds__(256) void transposeF2B(const float* __restrict__ in,
                                                    bf16* __restrict__ out,
                                                    int R, int C) {
    __shared__ float t[32][33];   // t[rlocal][clocal]
    const int c0 = blockIdx.x * 32, r0 = blockIdx.y * 32;
    const int tx = threadIdx.x & 31, ty = threadIdx.x >> 5;
#pragma unroll
    for (int i = 0; i < 4; i++)
        t[ty + i * 8][tx] = in[(size_t)(r0 + ty + i * 8) * C + c0 + tx];
    __syncthreads();
    const int ow = threadIdx.x >> 3;        // out row within tile (c-local)
    const int oc = (threadIdx.x & 7) * 4;   // out col within tile (r-local)
    bf16x4 vo;
#pragma unroll
    for (int k = 0; k < 4; k++) vo[k] = (bf16)t[oc + k][ow];
    *(bf16x4*)&out[(size_t)(c0 + ow) * R + r0 + oc] = vo;
}

// ---------------------------------------------------------------------------
// Fused QKV GEMM: C(M x 5120) = Ab(M x 2048, bf16) * WqkvT^T.
// R13 pipeline (BK=64 swizzled tiles + dbuf + counted vmcnt, verified) +
// R14: XCD chunked swizzle (T1, m157): L' = (L%8)*(nwg/8)+L/8 -> each XCD
// gets contiguous m-rows (A-panel L2 reuse). nwg=1280, %8==0 -> bijective.
// Epilogue routes: n<4096 -> Q ; 4096..4608 -> K ; >=4608 -> Vt (transposed).
// ---------------------------------------------------------------------------
__global__ __launch_bounds__(256) void gemm_qkv(const bf16* __restrict__ A,
                                                const bf16* __restrict__ BT,
                                                bf16* __restrict__ Q,
                                                bf16* __restrict__ K2,
                                                bf16* __restrict__ Vt) {
    constexpr int K = 2048;
    __shared__ __attribute__((aligned(16))) bf16 As[2][128 * 64];
    __shared__ __attribute__((aligned(16))) bf16 Bs[2][128 * 64];
    const int tid = threadIdx.x;
    const int wave = tid >> 6, lane = tid & 63;
    const int quad = lane >> 4, l16 = lane & 15;
    const int nwgx = gridDim.x;
    const int nwg = nwgx * gridDim.y;
    const int L = blockIdx.y * nwgx + blockIdx.x;
    const int Lp = (L & 7) * (nwg >> 3) + (L >> 3);
    const int m0 = (Lp / nwgx) * 128, n0 = (Lp % nwgx) * 128;
    const int wr = (wave >> 1) * 64, wc = (wave & 1) * 64;

    floatx4 acc[4][4] = {};

    const int wbase = wave * 32;
    const bf16* aSrc[4]; const bf16* bSrc[4];
#pragma unroll
    for (int j = 0; j < 4; j++) {
        const int r = wbase + 8 * j + (lane >> 3);
        aSrc[j] = A + (size_t)(m0 + r) * K + (((lane & 7) ^ (r & 7)) << 3);
        bSrc[j] = BT + (size_t)(n0 + r) * K + (((lane & 7) ^ (r & 7)) << 3);
    }

#define GSTAGE(buf, kk)                                                 \
    do {                                                                \
        bf16* aD_ = &As[buf][wbase * 64];                               \
        bf16* bD_ = &Bs[buf][wbase * 64];                               \
        _Pragma("unroll")                                               \
        for (int j_ = 0; j_ < 4; j_++) {                                \
            async_load16(aSrc[j_] + (kk), aD_ + j_ * 8 * 64);           \
            async_load16(bSrc[j_] + (kk), bD_ + j_ * 8 * 64);           \
        }                                                               \
    } while (0)

    constexpr int NKT = K / 64;
    GSTAGE(0, 0);
    int cur = 0;
    for (int kt = 0; kt < NKT; ++kt) {
        if (kt + 1 < NKT) {
            GSTAGE(cur ^ 1, (kt + 1) * 64);
            asm volatile("s_waitcnt vmcnt(8)" ::: "memory");  // tile t's DMAs done
        } else {
            asm volatile("s_waitcnt vmcnt(0)" ::: "memory");
        }
        __builtin_amdgcn_s_barrier();
        __builtin_amdgcn_sched_barrier(0);

#pragma unroll
        for (int ks = 0; ks < 2; ks++) {
            const int slot = ((ks * 4 + quad) ^ (l16 & 7)) << 3;
            bf16x8 af[4], bfr[4];
#pragma unroll
            for (int i = 0; i < 4; i++)
                af[i] = *(const bf16x8*)&As[cur][(wr + i * 16 + l16) * 64 + slot];
#pragma unroll
            for (int j = 0; j < 4; j++)
                bfr[j] = *(const bf16x8*)&Bs[cur][(wc + j * 16 + l16) * 64 + slot];
#pragma unroll
            for (int i = 0; i < 4; i++)
#pragma unroll
                for (int j = 0; j < 4; j++)
                    acc[i][j] = MFMA16(af[i], bfr[j], acc[i][j]);
        }
        __builtin_amdgcn_s_barrier();   // buf cur consumed by all waves
        cur ^= 1;
    }
#undef GSTAGE

    const int region = (n0 >= 4608) ? 2 : (n0 >= 4096 ? 1 : 0);
#pragma unroll
    for (int i = 0; i < 4; i++) {
#pragma unroll
        for (int j = 0; j < 4; j++) {
            const int row = m0 + wr + i * 16 + quad * 4;
            const int col = n0 + wc + j * 16 + l16;
            if (region == 0) {
#pragma unroll
                for (int r = 0; r < 4; r++)
                    Q[(size_t)(row + r) * 4096 + col] = (bf16)acc[i][j][r];
            } else if (region == 1) {
#pragma unroll
                for (int r = 0; r < 4; r++)
                    K2[(size_t)(row + r) * 512 + (col - 4096)] = (bf16)acc[i][j][r];
            } else {
                bf16x4 t;
#pragma unroll
                for (int r = 0; r < 4; r++) t[r] = (bf16)acc[i][j][r];
                *(bf16x4*)&Vt[(size_t)(col - 4608) * 4096 + row] = t;
            }
        }
    }
}

// ---------------------------------------------------------------------------
// O-projection GEMM: out(M x 2048, f32) = AO(M x 4096, bf16) * woT^T.
// R13 pipeline + R14 XCD swizzle (nwg=512, %8==0).
// ---------------------------------------------------------------------------
__global__ __launch_bounds__(256) void gemm_o(const bf16* __restrict__ A,
                                              const bf16* __restrict__ BT,
                                              float* __restrict__ C) {
    constexpr int K = 4096, N = 2048;
    __shared__ __attribute__((aligned(16))) bf16 As[2][128 * 64];
    __shared__ __attribute__((aligned(16))) bf16 Bs[2][128 * 64];
    const int tid = threadIdx.x;
    const int wave = tid >> 6, lane = tid & 63;
    const int quad = lane >> 4, l16 = lane & 15;
    const int nwgx = gridDim.x;
    const int nwg = nwgx * gridDim.y;
    const int L = blockIdx.y * nwgx + blockIdx.x;
    const int Lp = (L & 7) * (nwg >> 3) + (L >> 3);
    const int m0 = (Lp / nwgx) * 128, n0 = (Lp % nwgx) * 128;
    const int wr = (wave >> 1) * 64, wc = (wave & 1) * 64;

    floatx4 acc[4][4] = {};

    const int wbase = wave * 32;
    const bf16* aSrc[4]; const bf16* bSrc[4];
#pragma unroll
    for (int j = 0; j < 4; j++) {
        const int r = wbase + 8 * j + (lane >> 3);
        aSrc[j] = A + (size_t)(m0 + r) * K + (((lane & 7) ^ (r & 7)) << 3);
        bSrc[j] = BT + (size_t)(n0 + r) * K + (((lane & 7) ^ (r & 7)) << 3);
    }

#define GSTAGE(buf, kk)                                                 \
    do {                                                                \
        bf16* aD_ = &As[buf][wbase * 64];                               \
        bf16* bD_ = &Bs[buf][wbase * 64];                               \
        _Pragma("unroll")                                               \
        for (int j_ = 0; j_ < 4; j_++) {                                \
            async_load16(aSrc[j_] + (kk), aD_ + j_ * 8 * 64);           \
            async_load16(bSrc[j_] + (kk), bD_ + j_ * 8 * 64);           \
        }                                                               \
    } while (0)

    constexpr int NKT = K / 64;
    GSTAGE(0, 0);
    int cur = 0;
    for (int kt = 0; kt < NKT; ++kt) {
        if (kt + 1 < NKT) {
            GSTAGE(cur ^ 1, (kt + 1) * 64);
            asm volatile("s_waitcnt vmcnt(8)" ::: "memory");
        } else {
            asm volatile("s_waitcnt vmcnt(0)" ::: "memory");
        }
        __builtin_amdgcn_s_barrier();
        __builtin_amdgcn_sched_barrier(0);

#pragma unroll
        for (int ks = 0; ks < 2; ks++) {
            const int slot = ((ks * 4 + quad) ^ (l16 & 7)) << 3;
            bf16x8 af[4], bfr[4];
#pragma unroll
            for (int i = 0; i < 4; i++)
                af[i] = *(const bf16x8*)&As[cur][(wr + i * 16 + l16) * 64 + slot];
#pragma unroll
            for (int j = 0; j < 4; j++)
                bfr[j] = *(const bf16x8*)&Bs[cur][(wc + j * 16 + l16) * 64 + slot];
#pragma unroll
            for (int i = 0; i < 4; i++)
#pragma unroll
                for (int j = 0; j < 4; j++)
                    acc[i][j] = MFMA16(af[i], bfr[j], acc[i][j]);
        }
        __builtin_amdgcn_s_barrier();
        cur ^= 1;
    }
#undef GSTAGE

#pragma unroll
    for (int i = 0; i < 4; i++) {
#pragma unroll
        for (int j = 0; j < 4; j++) {
            const int row = m0 + wr + i * 16 + quad * 4;
            const int col = n0 + wc + j * 16 + l16;
#pragma unroll
            for (int r = 0; r < 4; r++)
                C[(size_t)(row + r) * N + col] = acc[i][j][r];
        }
    }
}

// ---------------------------------------------------------------------------
// Fused RMSNorm (D=128) + RoPE, in place on bf16 x.
// R14: vectorized (bf16x8 per lane, 16 lanes/row; G13). RoPE partner
// (e <-> e+64) fetched via shfl_xor(y, 8). `mul` folds the attention
// scale into Q (linear, commutes with RoPE); K passes 1.0f.
// grid: rows/16 blocks of 256 threads.
// ---------------------------------------------------------------------------
__global__ __launch_bounds__(256) void rmsrope(bf16* __restrict__ x,
                                               const float* __restrict__ w,
                                               const float* __restrict__ cosb,
                                               const float* __restrict__ sinb,
                                               int nh, int S, float mul) {
    const int l16 = threadIdx.x & 15;
    const int row = blockIdx.x * 16 + (threadIdx.x >> 4);
    const int s = (row / nh) % S;
    const int e0 = l16 * 8;
    bf16* p = x + (size_t)row * 128 + e0;
    const bf16x8 v = *(const bf16x8*)p;
    float xv[8], ssq = 0.f;
#pragma unroll
    for (int i = 0; i < 8; i++) { xv[i] = (float)v[i]; ssq += xv[i] * xv[i]; }
#pragma unroll
    for (int m = 1; m < 16; m <<= 1) ssq += __shfl_xor(ssq, m);
    const float rm = rsqrtf(ssq * (1.0f / 128.0f) + 1e-6f) * mul;
    const float4 w0 = *(const float4*)&w[e0];
    const float4 w1 = *(const float4*)&w[e0 + 4];
    float y[8];
    y[0] = w0.x * xv[0] * rm; y[1] = w0.y * xv[1] * rm;
    y[2] = w0.z * xv[2] * rm; y[3] = w0.w * xv[3] * rm;
    y[4] = w1.x * xv[4] * rm; y[5] = w1.y * xv[5] * rm;
    y[6] = w1.z * xv[6] * rm; y[7] = w1.w * xv[7] * rm;
    const float sgn = (l16 < 8) ? -1.f : 1.f;
    const float4 ca = *(const float4*)&cosb[s * 128 + e0];
    const float4 cb2 = *(const float4*)&cosb[s * 128 + e0 + 4];
    const float4 sa = *(const float4*)&sinb[s * 128 + e0];
    const float4 sb2 = *(const float4*)&sinb[s * 128 + e0 + 4];
    const float cc[8] = {ca.x, ca.y, ca.z, ca.w, cb2.x, cb2.y, cb2.z, cb2.w};
    const float ss[8] = {sa.x, sa.y, sa.z, sa.w, sb2.x, sb2.y, sb2.z, sb2.w};
    bf16x8 o;
#pragma unroll
    for (int i = 0; i < 8; i++) {
        const float rot = sgn * __shfl_xor(y[i], 8);
        o[i] = (bf16)(y[i] * cc[i] + rot * ss[i]);
    }
    *(bf16x8*)p = o;
}

// ---------------------------------------------------------------------------
// Causal GQA flash attention. R11 pipeline (verified) + R14:
//  - XCD chunked swizzle on flattened (bx,h,b): chunk of 64 logical blocks
//    = exactly one (b,kvh) KV working set (1MB) per XCD -> KV L2-resident.
//  - scale folded into Q upstream (rmsrope mul) -> exp(s) directly.
// QO: (B*S x 4096); K: (B*S x 512); Vt: (512 x B*S) d-major.
// grid (S/256, HQ, B), 512 threads.
// ---------------------------------------------------------------------------
__global__ __launch_bounds__(512, 4) void attn(bf16* QO,
                                               const bf16* __restrict__ Km,
                                               const bf16* __restrict__ Vt,
                                               int S) {
    __shared__ __attribute__((aligned(16))) bf16 Kl[2][64 * 128];
    __shared__ __attribute__((aligned(16))) bf16 Vl[2][128 * 64];
    __shared__ __attribute__((aligned(16))) bf16 Pl[8][16 * 40]; // per-wave P

    const int tid = threadIdx.x, wave = tid >> 6, lane = tid & 63;
    const int quad = lane >> 4, l16 = lane & 15;
    // XCD swizzle: physical linear id L runs on XCD L%8; give XCD x the
    // contiguous logical chunk [64x, 64x+64) = one (b,kvh) group.
    const int L = blockIdx.z * 256 + blockIdx.y * 8 + blockIdx.x;
    const int Lp = ((L & 7) << 6) + (L >> 3);
    const int bxs = Lp & 7;
    const int h = (Lp >> 3) & 31;
    const int b = Lp >> 8;
    const int kvh = h >> 3;

    const bf16* Kg = Km + (size_t)b * S * 512 + kvh * 128;
    const bf16* Vg = Vt + (size_t)kvh * 128 * 4096 + (size_t)b * S;

    const int krow0 = wave * 8 + (lane >> 4);
    const int krow1 = wave * 8 + 4 + (lane >> 4);
    const bf16* kSrc0 = Kg + (size_t)krow0 * 512 + (((lane & 15) ^ (krow0 & 7)) << 3);
    const bf16* kSrc1 = Kg + (size_t)krow1 * 512 + (((lane & 15) ^ (krow1 & 7)) << 3);
    const int vrow0 = wave * 16 + (lane >> 3);
    const int vrow1 = wave * 16 + 8 + (lane >> 3);
    const bf16* vSrc0 = Vg + (size_t)vrow0 * 4096 + (((lane & 7) ^ (vrow0 & 7)) << 3);
    const bf16* vSrc1 = Vg + (size_t)vrow1 * 4096 + (((lane & 7) ^ (vrow1 & 7)) << 3);

#define STAGE(buf, kk)                                                  \
    do {                                                                \
        bf16* kb_ = &Kl[buf][(wave * 8) * 128];                         \
        bf16* vb_ = &Vl[buf][(wave * 16) * 64];                         \
        async_load16(kSrc0 + (size_t)(kk) * 512, kb_);                  \
        async_load16(kSrc1 + (size_t)(kk) * 512, kb_ + 4 * 128);        \
        async_load16(vSrc0 + (kk), vb_);                                \
        async_load16(vSrc1 + (kk), vb_ + 8 * 64);                       \
    } while (0)

    bf16* pw = &Pl[wave][0];

#pragma unroll
    for (int half = 0; half < 2; half++) {
        const int qt = half ? (15 - bxs) : bxs;
        const int qb = qt * 128 + wave * 16;

        bf16x8 qf[4];
        {
            const bf16* qrow = QO + (size_t)(b * S + qb + l16) * 4096 + h * 128 + quad * 8;
#pragma unroll
            for (int c = 0; c < 4; c++) qf[c] = *(const bf16x8*)(qrow + c * 32);
        }

        floatx4 o_acc[8] = {};
        float l_i[4] = {0.f, 0.f, 0.f, 0.f};

        const int nt = 2 * (qt + 1);   // k-tiles of 64, block-uniform
        STAGE(0, 0);                   // prologue

        for (int kt = 0; kt < nt; ++kt) {
            const int k0 = kt * 64;
            const int cur = kt & 1;
            if (kt + 1 < nt) {
                STAGE(cur ^ 1, (kt + 1) * 64);
                asm volatile("s_waitcnt vmcnt(4)" ::: "memory");  // tile t's 4 DMAs done
            } else {
                asm volatile("s_waitcnt vmcnt(0)" ::: "memory");
            }
            __builtin_amdgcn_s_barrier();
            __builtin_amdgcn_sched_barrier(0);

            if (k0 <= qb + 15) {   // wave-uniform: skip fully-masked tiles
                const bf16* kl = &Kl[cur][0];
                const bf16* vl = &Vl[cur][0];

                floatx4 sc[4] = {};
#pragma unroll
                for (int c = 0; c < 4; c++) {
                    const int slot = ((c * 4 + quad) ^ (l16 & 7)) << 3;
#pragma unroll
                    for (int m = 0; m < 4; m++) {
                        const bf16x8 kf = *(const bf16x8*)&kl[(l16 + 16 * m) * 128 + slot];
                        sc[m] = MFMA16(qf[c], kf, sc[m]);
                    }
                }

#pragma unroll
                for (int ks = 0; ks < 2; ks++) {
                    const int kb = k0 + ks * 32;
                    if (kb > qb + 15) continue;          // fully masked half
                    const floatx4 s0 = sc[2 * ks], s1 = sc[2 * ks + 1];
                    if (kb + 31 > qb) {
#pragma unroll
                        for (int r = 0; r < 4; r++) {
                            const int qi = qb + quad * 4 + r;
                            const float p0 = (kb + l16 > qi) ? 0.f : __expf(s0[r]);
                            const float p1 = (kb + 16 + l16 > qi) ? 0.f : __expf(s1[r]);
                            l_i[r] += p0 + p1;
                            pw[(quad * 4 + r) * 40 + l16] = (bf16)p0;
                            pw[(quad * 4 + r) * 40 + l16 + 16] = (bf16)p1;
                        }
                    } else {
#pragma unroll
                        for (int r = 0; r < 4; r++) {
                            const float p0 = __expf(s0[r]);
                            const float p1 = __expf(s1[r]);
                            l_i[r] += p0 + p1;
                            pw[(quad * 4 + r) * 40 + l16] = (bf16)p0;
                            pw[(quad * 4 + r) * 40 + l16 + 16] = (bf16)p1;
                        }
                    }
                    const bf16x8 pa = *(const bf16x8*)&pw[l16 * 40 + quad * 8];
#pragma unroll
                    for (int c = 0; c < 8; c++) {
                        const int vps = ((ks * 4 + quad) ^ (l16 & 7)) << 3;
                        const bf16x8 vf = *(const bf16x8*)&vl[(c * 16 + l16) * 64 + vps];
                        o_acc[c] = MFMA16(pa, vf, o_acc[c]);
                    }
                }
            }
            __builtin_amdgcn_s_barrier();   // buf cur consumed by all waves
        }

#pragma unroll
        for (int r = 0; r < 4; r++) {
            float l = l_i[r];
            l += __shfl_xor(l, 1);
            l += __shfl_xor(l, 2);
            l += __shfl_xor(l, 4);
            l += __shfl_xor(l, 8);
            const float inv = (l > 0.f) ? 1.0f / l : 0.f;
            const size_t orow = (size_t)(b * S + qb + quad * 4 + r) * 4096 + h * 128;
#pragma unroll
            for (int c = 0; c < 8; c++)
                QO[orow + c * 16 + l16] = (bf16)(o_acc[c][r] * inv);
        }
    }
#undef STAGE
}

// ===========================================================================
// Fallback path (Round-4, proven; used only if ws_size < fast-path need)
// ===========================================================================
template <typename TA, typename TB, typename TC>
__global__ __launch_bounds__(256) void gemm_bn(const TA* __restrict__ A,
                                               const TB* __restrict__ B,
                                               TC* __restrict__ C,
                                               int M, int N, int K) {
    __shared__ __attribute__((aligned(16))) bf16 As[128 * 32];
    __shared__ __attribute__((aligned(16))) bf16 Bs[128 * 32];
    const int tid = threadIdx.x;
    const int wave = tid >> 6, lane = tid & 63;
    const int quad = lane >> 4, l16 = lane & 15;
    const int m0 = blockIdx.y * 128, n0 = blockIdx.x * 128;
    const int wr = (wave >> 1) * 64, wc = (wave & 1) * 64;
    floatx4 acc[4][4] = {};
    const int r0 = tid >> 2;
    const int kc = (tid & 3) * 8;
    const TA* gA0 = A + (size_t)(m0 + r0) * K + kc;
    const TA* gA1 = A + (size_t)(m0 + 64 + r0) * K + kc;
    const int kr = tid & 31;
    const int nc8 = (tid >> 5) * 8;
    const TB* gB = B + (size_t)kr * N + n0 + nc8;
    for (int k0 = 0; k0 < K; k0 += 32) {
        const bf16x8 a0 = load8(gA0 + k0);
        const bf16x8 a1 = load8(gA1 + k0);
        const TB* gBk = gB + (size_t)k0 * N;
        const bf16x8 b0 = load8(gBk);
        const bf16x8 b1 = load8(gBk + 64);
        __syncthreads();
        *(bf16x8*)&As[r0 * 32 + kc] = a0;
        *(bf16x8*)&As[(64 + r0) * 32 + kc] = a1;
#pragma unroll
        for (int j = 0; j < 8; j++) {
            Bs[(nc8 + j) * 32 + kr] = b0[j];
            Bs[(nc8 + 64 + j) * 32 + kr] = b1[j];
        }
        __syncthreads();
        bf16x8 af[4], bfr[4];
#pragma unroll
        for (int i = 0; i < 4; i++)
            af[i] = *(const bf16x8*)&As[(wr + i * 16 + l16) * 32 + quad * 8];
#pragma unroll
        for (int j = 0; j < 4; j++)
            bfr[j] = *(const bf16x8*)&Bs[(wc + j * 16 + l16) * 32 + quad * 8];
#pragma unroll
        for (int i = 0; i < 4; i++)
#pragma unroll
            for (int j = 0; j < 4; j++)
                acc[i][j] = MFMA16(af[i], bfr[j], acc[i][j]);
    }
#pragma unroll
    for (int i = 0; i < 4; i++) {
#pragma unroll
        for (int j = 0; j < 4; j++) {
            const int row = m0 + wr + i * 16 + quad * 4;
            const int col = n0 + wc + j * 16 + l16;
#pragma unroll
            for (int r = 0; r < 4; r++)
                C[(size_t)(row + r) * N + col] = (TC)acc[i][j][r];
        }
    }
}

__global__ __launch_bounds__(256) void attn_fb(bf16* QO,
                                               const bf16* __restrict__ Km,
                                               const bf16* __restrict__ Vm,
                                               int S) {
    __shared__ __attribute__((aligned(16))) bf16 Kl[32 * 136];
    __shared__ __attribute__((aligned(16))) bf16 Vl[128 * 40];
    __shared__ __attribute__((aligned(16))) bf16 Pl[4][16 * 40];
    const int tid = threadIdx.x, wave = tid >> 6, lane = tid & 63;
    const int quad = lane >> 4, l16 = lane & 15;
    const int q0 = blockIdx.x * 64;
    const int h = blockIdx.y, b = blockIdx.z;
    const int kvh = h >> 3;
    const int q_base = q0 + wave * 16;
    const float scale = 0.08838834764831845f;
    bf16x8 qf[4];
    {
        const bf16* qrow = QO + (size_t)(b * S + q_base + l16) * 4096 + h * 128 + quad * 8;
#pragma unroll
        for (int c = 0; c < 4; c++) qf[c] = *(const bf16x8*)(qrow + c * 32);
    }
    floatx4 o_acc[8] = {};
    float l_i[4] = {0.f, 0.f, 0.f, 0.f};
    const int kend = q0 + 64;
    for (int k0 = 0; k0 < kend; k0 += 32) {
#pragma unroll
        for (int it = 0; it < 2; ++it) {
            const int cc = tid + it * 256;
            const int row = cc >> 4;
            const int off = (cc & 15) * 8;
            const size_t gidx = (size_t)(b * S + k0 + row) * 512 + kvh * 128 + off;
            const bf16x8 kv = *(const bf16x8*)&Km[gidx];
            const bf16x8 vv = *(const bf16x8*)&Vm[gidx];
            *(bf16x8*)&Kl[row * 136 + off] = kv;
#pragma unroll
            for (int j = 0; j < 8; j++) Vl[(off + j) * 40 + row] = vv[j];
        }
        __syncthreads();
        if (k0 <= q_base + 15) {
            floatx4 sc0 = {}, sc1 = {};
#pragma unroll
            for (int c = 0; c < 4; c++) {
                bf16x8 b0 = *(const bf16x8*)&Kl[l16 * 136 + c * 32 + quad * 8];
                bf16x8 b1 = *(const bf16x8*)&Kl[(l16 + 16) * 136 + c * 32 + quad * 8];
                sc0 = MFMA16(qf[c], b0, sc0);
                sc1 = MFMA16(qf[c], b1, sc1);
            }
            const bool edge = (k0 + 31 > q_base);
            bf16* pw = &Pl[wave][0];
#pragma unroll
            for (int r = 0; r < 4; r++) {
                const int qi = q_base + quad * 4 + r;
                const bool mk0 = edge && (k0 + l16 > qi);
                const bool mk1 = edge && (k0 + 16 + l16 > qi);
                const float p0 = mk0 ? 0.f : __expf(sc0[r] * scale);
                const float p1 = mk1 ? 0.f : __expf(sc1[r] * scale);
                l_i[r] += p0 + p1;
                pw[(quad * 4 + r) * 40 + l16] = (bf16)p0;
                pw[(quad * 4 + r) * 40 + l16 + 16] = (bf16)p1;
            }
            const bf16x8 pa = *(const bf16x8*)&pw[l16 * 40 + quad * 8];
#pragma unroll
            for (int c = 0; c < 8; c++) {
                const bf16x8 vf = *(const bf16x8*)&Vl[(c * 16 + l16) * 40 + quad * 8];
                o_acc[c] = MFMA16(pa, vf, o_acc[c]);
            }
        }
        __syncthreads();
    }
#pragma unroll
    for (int r = 0; r < 4; r++) {
        float l = l_i[r];
        l += __shfl_xor(l, 1);
        l += __shfl_xor(l, 2);
        l += __shfl_xor(l, 4);
        l += __shfl_xor(l, 8);
        const float inv = (l > 0.f) ? 1.0f / l : 0.f;
        const size_t orow = (size_t)(b * S + q_base + quad * 4 + r) * 4096 + h * 128;
#pragma unroll
        for (int c = 0; c < 8; c++)
            QO[orow + c * 16 + l16] = (bf16)(o_acc[c][r] * inv);
    }
}

// ---------------------------------------------------------------------------
extern "C" void kernel_launch(void* const* d_in, const int* in_sizes, int n_in,
                              void* d_out, int out_size, void* d_ws, size_t ws_size,
                              hipStream_t stream) {
    const float* hidden = (const float*)d_in[0];
    const float* cosb = (const float*)d_in[1];
    const float* sinb = (const float*)d_in[2];
    const float* wq = (const float*)d_in[3];
    const float* wk = (const float*)d_in[4];
    const float* wv = (const float*)d_in[5];
    const float* wo = (const float*)d_in[6];
    const float* qnw = (const float*)d_in[7];
    const float* knw = (const float*)d_in[8];
    float* out = (float*)d_out;

    constexpr int B = 2, S = 2048, HID = 2048, HQ = 32, HKV = 4, D = 128;
    constexpr int M = B * S;       // 4096
    constexpr int NQ = HQ * D;     // 4096
    constexpr int NKV = HKV * D;   // 512
    constexpr int NQKV = NQ + 2 * NKV;  // 5120
    constexpr float SCALE = 0.08838834764831845f;

    // fast-path ws need (same as R5-proven 79.7MB): X slot is shared by
    // hiddenB (M*HID) and woT (HID*NQ) -- identical element counts.
    const size_t need = ((size_t)NQKV * HID + (size_t)HID * NQ +
                         (size_t)M * NQ + 2 * (size_t)M * NKV) * sizeof(bf16);

    if (ws_size >= need) {
        bf16* p = (bf16*)d_ws;
        bf16* wqkvT = p; p += (size_t)NQKV * HID;   // (5120 x 2048)
        bf16* X = p;     p += (size_t)HID * NQ;     // hiddenB then woT (8.39e6 el)
        bf16* Qb = p;    p += (size_t)M * NQ;
        bf16* Kb = p;    p += (size_t)M * NKV;
        bf16* Vt = p;    p += (size_t)NKV * M;      // (512 x 4096) d-major

        transposeF2B<<<dim3(NQ / 32, HID / 32), 256, 0, stream>>>(wq, wqkvT, HID, NQ);
        transposeF2B<<<dim3(NKV / 32, HID / 32), 256, 0, stream>>>(wk, wqkvT + (size_t)NQ * HID, HID, NKV);
        transposeF2B<<<dim3(NKV / 32, HID / 32), 256, 0, stream>>>(wv, wqkvT + (size_t)(NQ + NKV) * HID, HID, NKV);

        // hidden f32 -> bf16 into X
        f2b<<<dim3((M * HID) / (256 * 8)), 256, 0, stream>>>(hidden, X);

        gemm_qkv<<<dim3(NQKV / 128, M / 128), 256, 0, stream>>>(X, wqkvT, Qb, Kb, Vt);

        rmsrope<<<dim3(M * HQ / 16), 256, 0, stream>>>(Qb, qnw, cosb, sinb, HQ, S, SCALE);
        rmsrope<<<dim3(M * HKV / 16), 256, 0, stream>>>(Kb, knw, cosb, sinb, HKV, S, 1.0f);

        attn<<<dim3(S / 256, HQ, B), 512, 0, stream>>>(Qb, Kb, Vt, S);

        // X reused: wo^T lands where hiddenB was (stream-ordered, safe)
        transposeF2B<<<dim3(HID / 32, NQ / 32), 256, 0, stream>>>(wo, X, NQ, HID);
        gemm_o<<<dim3(HID / 128, M / 128), 256, 0, stream>>>(Qb, X, out);
    } else {
        bf16* p = (bf16*)d_ws;
        bf16* Qb = p;  p += (size_t)M * NQ;
        bf16* Kb = p;  p += (size_t)M * NKV;
        bf16* Vb = p;  p += (size_t)M * NKV;

        gemm_bn<float, float, bf16><<<dim3(NQ / 128, M / 128), 256, 0, stream>>>(hidden, wq, Qb, M, NQ, HID);
        gemm_bn<float, float, bf16><<<dim3(NKV / 128, M / 128), 256, 0, stream>>>(hidden, wk, Kb, M, NKV, HID);
        gemm_bn<float, float, bf16><<<dim3(NKV / 128, M / 128), 256, 0, stream>>>(hidden, wv, Vb, M, NKV, HID);
        rmsrope<<<dim3(M * HQ / 16), 256, 0, stream>>>(Qb, qnw, cosb, sinb, HQ, S, 1.0f);
        rmsrope<<<dim3(M * HKV / 16), 256, 0, stream>>>(Kb, knw, cosb, sinb, HKV, S, 1.0f);
        attn_fb<<<dim3(S / 64, HQ, B), 256, 0, stream>>>(Qb, Kb, Vb, S);
        gemm_bn<bf16, float, float><<<dim3(HID / 128, M / 128), 256, 0, stream>>>(Qb, wo, out, M, HID, NQ);
    }
}